// Round 4
// baseline (267.517 us; speedup 1.0000x reference)
//
#include <hip/hip_runtime.h>

// PositionalEncodingAngle: out[n, j] = sin/cos( |clip(x_n,±45)| / 45^(2*floor(e/2)/1024) )
// where e = j if x_n >= 0 else 1023-j; sin for even j, cos for odd j.
// Pair k = j/2 uses inv-denom exp2(-c*k) (x>=0) or exp2(-c*(511-k)) (x<0), c = log2(45)/512.
// Memory-bound: 268 MB f32 write-once output; ~40-42 us write floor at the measured fill rate.
// Budget: dur_us ~= 210 us harness fills (fixed, box-speed dependent) + kernel (~53 us).
//
// R8 (nt stores): fill-normalized NEUTRAL -> L2 write-allocate is not the gap. nt kept.
// R8 -> R9: attack the ~11 us above-floor residual as an occupancy/prologue effect:
//   - ROWS_PER_BLOCK 32 -> 16 (grid 4096): halves the xv[] register preload and the
//     per-block serial prologue, cuts VGPR (~-16) toward 8 waves/SIMD residency,
//     doubles block parallelism for smoother ramp/drain.
//   - clamp+abs fused to fminf(fabsf(x),45) (sign from raw x) - one VALU fewer/row.

#define PE_D 1024
#define PE_RES 45.0f
#define ROWS_PER_BLOCK 16

typedef float f32x4 __attribute__((ext_vector_type(4)));

__global__ __launch_bounds__(256) void PositionalEncodingAngle_kernel(
    const float* __restrict__ x, float* __restrict__ out) {
    const int tid = threadIdx.x;                 // 0..255 -> j = 4*tid..4*tid+3 (pairs 2*tid, 2*tid+1)
    const int n0  = blockIdx.x * ROWS_PER_BLOCK;

    // c = log2(45)/512
    const float c = 0.010726275578769f;
    const int   k0 = 2 * tid;

    // Loop-invariant inverse denominators for both sign branches.
    const float e_pos0 = exp2f(-c * (float)(k0));
    const float e_pos1 = exp2f(-c * (float)(k0 + 1));
    const float e_neg0 = exp2f(-c * (float)(511 - k0));
    const float e_neg1 = exp2f(-c * (float)(510 - k0));

    // Preload the block's positions (wave-uniform loads -> scalar regs, L2-hit).
    float xv[ROWS_PER_BLOCK];
#pragma unroll
    for (int r = 0; r < ROWS_PER_BLOCK; ++r) xv[r] = x[n0 + r];

    f32x4* outv = reinterpret_cast<f32x4*>(out);

#pragma unroll
    for (int r = 0; r < ROWS_PER_BLOCK; r += 4) {
        f32x4 o[4];
#pragma unroll
        for (int i = 0; i < 4; ++i) {
            const float xr = xv[r + i];
            const float a  = fminf(fabsf(xr), PE_RES);   // |clip(x,±45)| == min(|x|,45)
            const bool  p  = (xr >= 0.0f);
            const float a0 = a * (p ? e_pos0 : e_neg0);
            const float a1 = a * (p ? e_pos1 : e_neg1);
            o[i].x = __sinf(a0); o[i].y = __cosf(a0);
            o[i].z = __sinf(a1); o[i].w = __cosf(a1);
        }
#pragma unroll
        for (int i = 0; i < 4; ++i)
            __builtin_nontemporal_store(o[i], &outv[(size_t)(n0 + r + i) * (PE_D / 4) + tid]);
    }
}

extern "C" void kernel_launch(void* const* d_in, const int* in_sizes, int n_in,
                              void* d_out, int out_size, void* d_ws, size_t ws_size,
                              hipStream_t stream) {
    const float* x = (const float*)d_in[0];
    float* out = (float*)d_out;
    const int N = out_size / PE_D;               // nbatch * nsources = 65536 (multiple of 16)
    const int grid = N / ROWS_PER_BLOCK;         // 4096 blocks = 16/CU
    PositionalEncodingAngle_kernel<<<grid, 256, 0, stream>>>(x, out);
}